// Round 2
// baseline (681.235 us; speedup 1.0000x reference)
//
#include <hip/hip_runtime.h>
#include <cstdint>
#include <cstddef>

typedef __bf16 bf16_t;
typedef __bf16 bf16x4 __attribute__((ext_vector_type(4)));
typedef __bf16 bf16x8 __attribute__((ext_vector_type(8)));
typedef float f32x4 __attribute__((ext_vector_type(4)));

#define B_ 4
#define T_ 2048
#define DIM_ 2048
#define H_ 16
#define KVH_ 4
#define HD_ 128
#define QKV_ 3072
// SCALE * log2(e): folded into q rows in the gemm_qkv epilogue; attn uses exp2.
#define QSCALE (0.08838834764831845f * 1.4426950408889634f)

// ---------------------------------------------------------------------------
// async global->LDS, 16B per lane. LDS dest = wave-uniform base + lane*16B.
// Dest pointer arithmetic is in ELEMENTS: 8 bf16 = 16B per lane.
// ---------------------------------------------------------------------------
__device__ __forceinline__ void gload16(const bf16_t* g, bf16_t* l) {
  __builtin_amdgcn_global_load_lds(
      (const __attribute__((address_space(1))) unsigned int*)g,
      (__attribute__((address_space(3))) unsigned int*)l, 16, 0, 0);
}

// ---------------------------------------------------------------------------
// fused fp32 -> bf16 convert for all five inputs (one launch).
// Segments (float4 units): x 4194304 | Wq 1048576 | Wk 262144 | Wv 262144 | Wp 1048576
// ---------------------------------------------------------------------------
__global__ __launch_bounds__(256) void cvt_all(const float4* __restrict__ x,
                                               const float4* __restrict__ wq,
                                               const float4* __restrict__ wk,
                                               const float4* __restrict__ wv,
                                               const float4* __restrict__ wp,
                                               bf16x4* __restrict__ xb,
                                               bf16x4* __restrict__ wqkvb,
                                               bf16x4* __restrict__ wpb) {
  int i = blockIdx.x * 256 + threadIdx.x;
  const float4* s;
  bf16x4* dst;
  int off;
  if (i < 4194304) { s = x; dst = xb; off = i; }
  else if (i < 5242880) { s = wq; dst = wqkvb; off = i - 4194304; }
  else if (i < 5505024) { s = wk; dst = wqkvb + 1048576; off = i - 5242880; }
  else if (i < 5767168) { s = wv; dst = wqkvb + 1310720; off = i - 5505024; }
  else { s = wp; dst = wpb; off = i - 5767168; }
  float4 v = s[off];
  bf16x4 o = {(__bf16)v.x, (__bf16)v.y, (__bf16)v.z, (__bf16)v.w};
  dst[off] = o;
}

// ---------------------------------------------------------------------------
// GEMM: C(MxN) = A(MxK) @ B(NxK)^T, bf16 in, fp32 acc. m97 structure.
// Used for the output projection (fp32 out).
// ---------------------------------------------------------------------------
__global__ __launch_bounds__(256) void gemm_bt(const bf16_t* __restrict__ A,
                                               const bf16_t* __restrict__ B,
                                               void* __restrict__ Cp,
                                               int M, int N, int K, int out_bf16) {
  __shared__ bf16_t As[128 * 32];
  __shared__ bf16_t Bs[128 * 32];
  const int tid = threadIdx.x;
  const int w = tid >> 6, lane = tid & 63;
  const int m_lane = lane & 15, quad = lane >> 4;
  const int wr = w >> 1, wc = w & 1;
  const int rowBase = blockIdx.y * 128, colBase = blockIdx.x * 128;

  f32x4 acc[4][4];
#pragma unroll
  for (int i = 0; i < 4; ++i)
#pragma unroll
    for (int j = 0; j < 4; ++j) acc[i][j] = (f32x4){0.f, 0.f, 0.f, 0.f};

  const int nk = K >> 5;
  for (int kk = 0; kk < nk; ++kk) {
    const int k0 = kk << 5;
#pragma unroll
    for (int i2 = 0; i2 < 2; ++i2) {
      int idx = i2 * 256 + tid;
      int row = idx >> 2, kc = idx & 3;
      gload16(A + (size_t)(rowBase + row) * K + k0 + kc * 8, &As[idx * 8]);
      gload16(B + (size_t)(colBase + row) * K + k0 + kc * 8, &Bs[idx * 8]);
    }
    __syncthreads();
    bf16x8 a[4], bb[4];
#pragma unroll
    for (int i = 0; i < 4; ++i)
      a[i] = *(const bf16x8*)&As[(wr * 64 + i * 16 + m_lane) * 32 + quad * 8];
#pragma unroll
    for (int j = 0; j < 4; ++j)
      bb[j] = *(const bf16x8*)&Bs[(wc * 64 + j * 16 + m_lane) * 32 + quad * 8];
#pragma unroll
    for (int i = 0; i < 4; ++i)
#pragma unroll
      for (int j = 0; j < 4; ++j)
        acc[i][j] = __builtin_amdgcn_mfma_f32_16x16x32_bf16(a[i], bb[j], acc[i][j], 0, 0, 0);
    __syncthreads();
  }

  if (out_bf16) {
    bf16_t* C = (bf16_t*)Cp;
#pragma unroll
    for (int i = 0; i < 4; ++i)
#pragma unroll
      for (int j = 0; j < 4; ++j)
#pragma unroll
        for (int r = 0; r < 4; ++r) {
          int row = rowBase + wr * 64 + i * 16 + quad * 4 + r;
          int col = colBase + wc * 64 + j * 16 + m_lane;
          C[(size_t)row * N + col] = (bf16_t)acc[i][j][r];
        }
  } else {
    float* C = (float*)Cp;
#pragma unroll
    for (int i = 0; i < 4; ++i)
#pragma unroll
      for (int j = 0; j < 4; ++j)
#pragma unroll
        for (int r = 0; r < 4; ++r) {
          int row = rowBase + wr * 64 + i * 16 + quad * 4 + r;
          int col = colBase + wc * 64 + j * 16 + m_lane;
          C[(size_t)row * N + col] = acc[i][j][r];
        }
  }
}

// ---------------------------------------------------------------------------
// QKV GEMM with fused epilogue: M=8192, N=3072, K=2048.
// Col-tile bx: 0..15 = q heads, 16..19 = k heads, 20..23 = v heads.
// q/k tiles: RMSNorm (fp32 acc, cross-wave LDS reduce) + RoPE (+gain*QSCALE
// for q). A 128-col tile is exactly one head; RoPE pairs (d,d+32) are
// lane-local (fragment j and j+2). v tiles: raw store + transposed store
// into vt (B,KVH,HD,T) -- replaces the separate vtrans kernel.
// ---------------------------------------------------------------------------
__global__ __launch_bounds__(256) void gemm_qkv(const bf16_t* __restrict__ A,
                                                const bf16_t* __restrict__ Bw,
                                                bf16_t* __restrict__ qkv,
                                                bf16_t* __restrict__ vt,
                                                const float* __restrict__ gain) {
  __shared__ bf16_t As[128 * 32];
  __shared__ bf16_t Bs[128 * 32];
  __shared__ float ssbuf[2][128];
  const int tid = threadIdx.x;
  const int w = tid >> 6, lane = tid & 63;
  const int m = lane & 15, quad = lane >> 4;
  const int wr = w >> 1, wc = w & 1;
  const int rowBase = blockIdx.y * 128, colBase = blockIdx.x * 128;

  f32x4 acc[4][4];
#pragma unroll
  for (int i = 0; i < 4; ++i)
#pragma unroll
    for (int j = 0; j < 4; ++j) acc[i][j] = (f32x4){0.f, 0.f, 0.f, 0.f};

  for (int kk = 0; kk < 64; ++kk) {
    const int k0 = kk << 5;
#pragma unroll
    for (int i2 = 0; i2 < 2; ++i2) {
      int idx = i2 * 256 + tid;
      int row = idx >> 2, kc = idx & 3;
      gload16(A + (size_t)(rowBase + row) * 2048 + k0 + kc * 8, &As[idx * 8]);
      gload16(Bw + (size_t)(colBase + row) * 2048 + k0 + kc * 8, &Bs[idx * 8]);
    }
    __syncthreads();
    bf16x8 a[4], bb[4];
#pragma unroll
    for (int i = 0; i < 4; ++i)
      a[i] = *(const bf16x8*)&As[(wr * 64 + i * 16 + m) * 32 + quad * 8];
#pragma unroll
    for (int j = 0; j < 4; ++j)
      bb[j] = *(const bf16x8*)&Bs[(wc * 64 + j * 16 + m) * 32 + quad * 8];
#pragma unroll
    for (int i = 0; i < 4; ++i)
#pragma unroll
      for (int j = 0; j < 4; ++j)
        acc[i][j] = __builtin_amdgcn_mfma_f32_16x16x32_bf16(a[i], bb[j], acc[i][j], 0, 0, 0);
    __syncthreads();
  }

  const int bx = blockIdx.x;
  if (bx < 20) {
    // ---- q/k epilogue: RMSNorm + RoPE
    const float g = (bx < 16) ? gain[bx] * QSCALE : 1.0f;
    // per-row sum of squares: in-lane (4 cols) -> 16-lane tree -> LDS cross-wave
#pragma unroll
    for (int i = 0; i < 4; ++i) {
      float ssp[4];
#pragma unroll
      for (int r = 0; r < 4; ++r) {
        float s = 0.f;
#pragma unroll
        for (int j = 0; j < 4; ++j) s += acc[i][j][r] * acc[i][j][r];
#pragma unroll
        for (int off = 1; off <= 8; off <<= 1) s += __shfl_xor(s, off);
        ssp[r] = s;
      }
      if (m == 0) {
#pragma unroll
        for (int r = 0; r < 4; ++r) ssbuf[wc][wr * 64 + i * 16 + quad * 4 + r] = ssp[r];
      }
    }
    __syncthreads();
    // inv_freq for this lane's two rope pair-indices p=m and p=16+m
    const float if0 = exp2f(-(float)m * 0.4152410118609203f);
    const float if1 = exp2f(-(float)(16 + m) * 0.4152410118609203f);
#pragma unroll
    for (int i = 0; i < 4; ++i) {
#pragma unroll
      for (int r = 0; r < 4; ++r) {
        const int ridx = wr * 64 + i * 16 + quad * 4 + r;
        const int row = rowBase + ridx;
        const float rn = rsqrtf((ssbuf[0][ridx] + ssbuf[1][ridx]) * (1.f / 128.f) + 1e-6f);
        float v0 = acc[i][0][r] * rn, v1 = acc[i][1][r] * rn;
        float v2 = acc[i][2][r] * rn, v3 = acc[i][3][r] * rn;
        float o0 = v0, o1 = v1, o2 = v2, o3 = v3;
        if (wc == 0) {  // cols 0..63 of head: rotate pairs (d, d+32)
          const float t = (float)(row & (T_ - 1));
          const float a0 = t * if0, a1 = t * if1;
          const float c0 = cosf(a0), s0 = sinf(a0);
          const float c1 = cosf(a1), s1 = sinf(a1);
          o0 = v0 * c0 - v2 * s0;
          o1 = v1 * c1 - v3 * s1;
          o2 = v2 * c0 + v0 * s0;
          o3 = v3 * c1 + v1 * s1;
        }
        bf16_t* out = qkv + (size_t)row * QKV_ + colBase + wc * 64 + m;
        out[0]  = (bf16_t)(o0 * g);
        out[16] = (bf16_t)(o1 * g);
        out[32] = (bf16_t)(o2 * g);
        out[48] = (bf16_t)(o3 * g);
      }
    }
  } else {
    // ---- v epilogue: raw row-major store + transposed store into vt
    const int kvh = bx - 20;
#pragma unroll
    for (int i = 0; i < 4; ++i)
#pragma unroll
      for (int j = 0; j < 4; ++j) {
        const int row0 = rowBase + wr * 64 + i * 16 + quad * 4;
        const int d = wc * 64 + j * 16 + m;
        bf16x4 pv;
#pragma unroll
        for (int r = 0; r < 4; ++r) {
          pv[r] = (bf16_t)acc[i][j][r];
          qkv[(size_t)(row0 + r) * QKV_ + colBase + d] = pv[r];
        }
        const int b = row0 >> 11, t0 = row0 & (T_ - 1);
        *(bf16x4*)(vt + ((size_t)(b * KVH_ + kvh) * HD_ + d) * T_ + t0) = pv;
      }
  }
}

// ---------------------------------------------------------------------------
// Flash attention, S^T formulation, software-pipelined. R7:
//  * grid (8,16,4) RESTORED: block handles q-tiles {15-x, x} -> uniform 68
//    K-iterations per block (load balance dominates co-residency; the R6
//    one-tile-per-block split regressed 191->283us from straggler tiles).
//  * T13 defer-rescale KEPT: skip {exp2, l*=al, o*=al (64 v_mul/lane)}
//    unless a row's tile-max exceeds running max by >10 log2-units.
//  * T5 s_setprio(1) around MFMA clusters (independent blocks per CU ->
//    waves at different phases; the regime where m191 measured +4-7%).
// 4 waves x 32 q-rows. K-step 32, double-buffered K/V LDS via
// global_load_lds. LDS read offsets hoisted out of the K-loop.
// ---------------------------------------------------------------------------
__global__ __launch_bounds__(256) void attn_kernel(const bf16_t* __restrict__ qkv,
                                                   const bf16_t* __restrict__ vt,
                                                   bf16_t* __restrict__ y) {
  __shared__ __align__(16) bf16_t Ks[2][32 * 128];  // [key][hd], chunk slot s holds src chunk s^(key&15)
  __shared__ __align__(16) bf16_t Vs[2][128 * 32];  // [d][key], slot c holds src chunk c^((d^(d>>2))&3)
  __shared__ __align__(16) bf16_t Ps[4][32 * 40];   // per-wave P [qrow][key], stride 40

  const int tid = threadIdx.x;
  const int w = tid >> 6, lane = tid & 63;
  const int m = lane & 15, q = lane >> 4;
  const int h = blockIdx.y, b = blockIdx.z, kvh = h >> 2;

  const bf16_t* qptr = qkv + (size_t)(b * T_) * QKV_ + h * HD_;
  const bf16_t* kptr = qkv + (size_t)(b * T_) * QKV_ + DIM_ + kvh * HD_;
  const bf16_t* vptr = qkv + (size_t)(b * T_) * QKV_ + DIM_ + KVH_ * HD_ + kvh * HD_;
  const bf16_t* vtptr = vt + (size_t)(b * KVH_ + kvh) * HD_ * T_;

  // per-thread staging indices (fixed): K 512 chunks, V 512 chunks
  const int kKey0 = tid >> 4, kC0 = tid & 15;
  const int kKey1 = (256 + tid) >> 4, kC1 = tid & 15;
  const int vD0 = tid >> 2, vC0 = tid & 3;
  const int vD1 = (256 + tid) >> 2, vC1 = tid & 3;
  const int vS0 = (vD0 ^ (vD0 >> 2)) & 3, vS1 = (vD1 ^ (vD1 >> 2)) & 3;

  // hoisted LDS read offsets (loop-invariant; elements)
  int koff[2][4], voff[8], poff[2];
#pragma unroll
  for (int kf = 0; kf < 2; ++kf)
#pragma unroll
    for (int c = 0; c < 4; ++c)
      koff[kf][c] = (kf * 16 + m) * 128 + (((c * 4 + q) ^ m) & 15) * 8;
#pragma unroll
  for (int f = 0; f < 8; ++f) {
    const int d = f * 16 + m;
    voff[f] = d * 32 + ((q ^ ((d ^ (d >> 2)) & 3)) & 3) * 8;
  }
#pragma unroll
  for (int qf = 0; qf < 2; ++qf) poff[qf] = (qf * 16 + m) * 40 + q * 8;

#pragma unroll 1
  for (int ti = 0; ti < 2; ++ti) {
    const int qb = ((ti == 0) ? (15 - (int)blockIdx.x) : (int)blockIdx.x) * 128;
    const int qbw = qb + w * 32;
    const int nk = (qb >> 5) + 4;

    // Q fragments (B-operand): aq[qf][c] = Q[qbw+qf*16+m][c*32+q*8 ..+8]
    bf16x8 aq[2][4];
#pragma unroll
    for (int qf = 0; qf < 2; ++qf)
#pragma unroll
      for (int c = 0; c < 4; ++c)
        aq[qf][c] = *(const bf16x8*)(qptr + (size_t)(qbw + qf * 16 + m) * QKV_ + c * 32 + q * 8);

    f32x4 o[2][8];
#pragma unroll
    for (int qf = 0; qf < 2; ++qf)
#pragma unroll
      for (int f = 0; f < 8; ++f) o[qf][f] = (f32x4){0.f, 0.f, 0.f, 0.f};
    float m_r[2] = {-1e30f, -1e30f};
    float l_r[2] = {0.f, 0.f};

    // prefetch tile 0 (elem offset = chunk_id * 8)
    {
      gload16(kptr + (size_t)kKey0 * QKV_ + ((kC0 ^ kKey0) & 15) * 8, &Ks[0][tid * 8]);
      gload16(kptr + (size_t)kKey1 * QKV_ + ((kC1 ^ kKey1) & 15) * 8, &Ks[0][(256 + tid) * 8]);
      gload16(vtptr + (size_t)vD0 * T_ + (vC0 ^ vS0) * 8, &Vs[0][tid * 8]);
      gload16(vtptr + (size_t)vD1 * T_ + (vC1 ^ vS1) * 8, &Vs[0][(256 + tid) * 8]);
    }

#pragma unroll 1
    for (int it = 0; it < nk; ++it) {
      const int kb = it << 5;
      __syncthreads();  // drains tile-it loads (issued one full iter ago)

      if (it + 1 < nk) {  // issue tile it+1 into the other buffer
        const int kb2 = kb + 32;
        bf16_t* Kb = Ks[(it + 1) & 1];
        bf16_t* Vb = Vs[(it + 1) & 1];
        gload16(kptr + (size_t)(kb2 + kKey0) * QKV_ + ((kC0 ^ kKey0) & 15) * 8, &Kb[tid * 8]);
        gload16(kptr + (size_t)(kb2 + kKey1) * QKV_ + ((kC1 ^ kKey1) & 15) * 8, &Kb[(256 + tid) * 8]);
        gload16(vtptr + (size_t)vD0 * T_ + kb2 + (vC0 ^ vS0) * 8, &Vb[tid * 8]);
        gload16(vtptr + (size_t)vD1 * T_ + kb2 + (vC1 ^ vS1) * 8, &Vb[(256 + tid) * 8]);
      }

      if (kb > qbw + 31) continue;  // whole key-tile masked for this wave
      const bf16_t* Kb = Ks[it & 1];
      const bf16_t* Vb = Vs[it & 1];

      // ---- S^T = K . Q^T   (16 MFMA, 8 ds_read_b128)
      f32x4 S[2][2];
#pragma unroll
      for (int qf = 0; qf < 2; ++qf)
#pragma unroll
        for (int kf = 0; kf < 2; ++kf) S[qf][kf] = (f32x4){0.f, 0.f, 0.f, 0.f};
      __builtin_amdgcn_s_setprio(1);
#pragma unroll
      for (int kf = 0; kf < 2; ++kf)
#pragma unroll
        for (int c = 0; c < 4; ++c) {
          bf16x8 ak = *(const bf16x8*)&Kb[koff[kf][c]];
          S[0][kf] = __builtin_amdgcn_mfma_f32_16x16x32_bf16(ak, aq[0][c], S[0][kf], 0, 0, 0);
          S[1][kf] = __builtin_amdgcn_mfma_f32_16x16x32_bf16(ak, aq[1][c], S[1][kf], 0, 0, 0);
        }
      __builtin_amdgcn_s_setprio(0);

      const bool needmask = (kb + 31) > qbw;
#pragma unroll
      for (int qf = 0; qf < 2; ++qf) {
        const int qrow = qbw + qf * 16 + m;
        if (needmask) {
#pragma unroll
          for (int kf = 0; kf < 2; ++kf)
#pragma unroll
            for (int r = 0; r < 4; ++r) {
              int key = kb + kf * 16 + q * 4 + r;
              if (key > qrow) S[qf][kf][r] = -1e30f;
            }
        }
        float t = -1e30f;
#pragma unroll
        for (int kf = 0; kf < 2; ++kf)
          t = fmaxf(t, fmaxf(fmaxf(S[qf][kf][0], S[qf][kf][1]),
                             fmaxf(S[qf][kf][2], S[qf][kf][3])));
        t = fmaxf(t, __shfl_xor(t, 16));
        t = fmaxf(t, __shfl_xor(t, 32));
        // T13 defer-rescale: only pay the O-wide rescale when the running max
        // actually grows by >10 log2-units (first tile always takes it).
        if (__any(t > m_r[qf] + 10.0f)) {
          const float mn = fmaxf(m_r[qf], t);
          const float al = exp2f(m_r[qf] - mn);
          m_r[qf] = mn;
          l_r[qf] *= al;
#pragma unroll
          for (int f = 0; f < 8; ++f) o[qf][f] = o[qf][f] * al;
        }
        const float mr = m_r[qf];
        float rs = 0.f;
#pragma unroll
        for (int kf = 0; kf < 2; ++kf)
#pragma unroll
          for (int r = 0; r < 4; ++r) {
            float p = exp2f(S[qf][kf][r] - mr);
            S[qf][kf][r] = p;
            rs += p;
          }
        rs += __shfl_xor(rs, 16);
        rs += __shfl_xor(rs, 32);
        l_r[qf] += rs;
#pragma unroll
        for (int kf = 0; kf < 2; ++kf) {
          bf16x4 pk = {(__bf16)S[qf][kf][0], (__bf16)S[qf][kf][1],
                       (__bf16)S[qf][kf][2], (__bf16)S[qf][kf][3]};
          *(bf16x4*)&Ps[w][(qf * 16 + m) * 40 + kf * 16 + q * 4] = pk;
        }
      }
      asm volatile("s_waitcnt lgkmcnt(0)" ::: "memory");

      // ---- PV: O^T += V^T . P^T  (16 MFMA, 10 ds_read_b128)
      bf16x8 Pb[2];
#pragma unroll
      for (int qf = 0; qf < 2; ++qf)
        Pb[qf] = *(const bf16x8*)&Ps[w][poff[qf]];
      __builtin_amdgcn_s_setprio(1);
#pragma unroll
      for (int f = 0; f < 8; ++f) {
        bf16x8 av = *(const bf16x8*)&Vb[voff[f]];
        o[0][f] = __builtin_amdgcn_mfma_f32_16x16x32_bf16(av, Pb[0], o[0][f], 0, 0, 0);
        o[1][f] = __builtin_amdgcn_mfma_f32_16x16x32_bf16(av, Pb[1], o[1][f], 0, 0, 0);
      }
      __builtin_amdgcn_s_setprio(0);
    }

    // ---- epilogue: y = o/l minus projection onto normalized v row
#pragma unroll
    for (int qf = 0; qf < 2; ++qf) {
      const int trow = qbw + qf * 16 + m;
      const float linv = 1.f / l_r[qf];
      bf16x4 vv[8];
      float n2 = 0.f, dp = 0.f;
#pragma unroll
      for (int f = 0; f < 8; ++f) {
        vv[f] = *(const bf16x4*)(vptr + (size_t)trow * QKV_ + f * 16 + q * 4);
#pragma unroll
        for (int r = 0; r < 4; ++r) {
          float v = (float)vv[f][r];
          n2 += v * v;
          dp += o[qf][f][r] * linv * v;
        }
      }
      n2 += __shfl_xor(n2, 16); n2 += __shfl_xor(n2, 32);
      dp += __shfl_xor(dp, 16); dp += __shfl_xor(dp, 32);
      float d = fmaxf(sqrtf(n2), 1e-12f);
      float coef = dp / (d * d);
#pragma unroll
      for (int f = 0; f < 8; ++f) {
        bf16x4 yo;
#pragma unroll
        for (int r = 0; r < 4; ++r)
          yo[r] = (bf16_t)(o[qf][f][r] * linv - coef * (float)vv[f][r]);
        *(bf16x4*)(y + (size_t)(b * T_ + trow) * DIM_ + h * HD_ + f * 16 + q * 4) = yo;
      }
    }
    __syncthreads();  // protect K/V buffers before next q-tile's prefetch
  }
}

// ---------------------------------------------------------------------------
extern "C" void kernel_launch(void* const* d_in, const int* in_sizes, int n_in,
                              void* d_out, int out_size, void* d_ws, size_t ws_size,
                              hipStream_t stream) {
  const float* x = (const float*)d_in[0];
  const float* Wq = (const float*)d_in[1];
  const float* Wk = (const float*)d_in[2];
  const float* Wv = (const float*)d_in[3];
  const float* Wp = (const float*)d_in[4];
  const float* qg = (const float*)d_in[5];

  bf16_t* xbf = (bf16_t*)d_ws;                        // 8192*2048
  bf16_t* wqkv = xbf + (size_t)8192 * 2048;           // 3072*2048
  bf16_t* wproj = wqkv + (size_t)3072 * 2048;         // 2048*2048
  bf16_t* qkv = wproj + (size_t)2048 * 2048;          // 8192*3072
  bf16_t* vt = qkv + (size_t)8192 * 3072;             // 16*128*2048
  bf16_t* ybf = xbf;                                  // reuse after gemm_qkv

  cvt_all<<<26624, 256, 0, stream>>>((const float4*)x, (const float4*)Wq,
                                     (const float4*)Wk, (const float4*)Wv,
                                     (const float4*)Wp, (bf16x4*)xbf,
                                     (bf16x4*)wqkv, (bf16x4*)wproj);
  gemm_qkv<<<dim3(24, 64), 256, 0, stream>>>(xbf, wqkv, qkv, vt, qg);
  attn_kernel<<<dim3(8, 16, 4), 256, 0, stream>>>(qkv, vt, ybf);
  gemm_bt<<<dim3(16, 64), 256, 0, stream>>>(ybf, wproj, d_out, 8192, 2048, 2048, 0);
}

// Round 3
// 587.788 us; speedup vs baseline: 1.1590x; 1.1590x over previous
//
#include <hip/hip_runtime.h>
#include <cstdint>
#include <cstddef>

typedef __bf16 bf16_t;
typedef __bf16 bf16x4 __attribute__((ext_vector_type(4)));
typedef __bf16 bf16x8 __attribute__((ext_vector_type(8)));
typedef float f32x4 __attribute__((ext_vector_type(4)));

#define B_ 4
#define T_ 2048
#define DIM_ 2048
#define H_ 16
#define KVH_ 4
#define HD_ 128
#define QKV_ 3072
// SCALE * log2(e): folded into q rows in the gemm_qkv epilogue; attn uses exp2.
#define QSCALE (0.08838834764831845f * 1.4426950408889634f)

// ---------------------------------------------------------------------------
// async global->LDS, 16B per lane. LDS dest = wave-uniform base + lane*16B.
// Dest pointer arithmetic is in ELEMENTS: 8 bf16 = 16B per lane.
// ---------------------------------------------------------------------------
__device__ __forceinline__ void gload16(const bf16_t* g, bf16_t* l) {
  __builtin_amdgcn_global_load_lds(
      (const __attribute__((address_space(1))) unsigned int*)g,
      (__attribute__((address_space(3))) unsigned int*)l, 16, 0, 0);
}

// ---------------------------------------------------------------------------
// fused fp32 -> bf16 convert for all five inputs (one launch).
// Segments (float4 units): x 4194304 | Wq 1048576 | Wk 262144 | Wv 262144 | Wp 1048576
// ---------------------------------------------------------------------------
__global__ __launch_bounds__(256) void cvt_all(const float4* __restrict__ x,
                                               const float4* __restrict__ wq,
                                               const float4* __restrict__ wk,
                                               const float4* __restrict__ wv,
                                               const float4* __restrict__ wp,
                                               bf16x4* __restrict__ xb,
                                               bf16x4* __restrict__ wqkvb,
                                               bf16x4* __restrict__ wpb) {
  int i = blockIdx.x * 256 + threadIdx.x;
  const float4* s;
  bf16x4* dst;
  int off;
  if (i < 4194304) { s = x; dst = xb; off = i; }
  else if (i < 5242880) { s = wq; dst = wqkvb; off = i - 4194304; }
  else if (i < 5505024) { s = wk; dst = wqkvb + 1048576; off = i - 5242880; }
  else if (i < 5767168) { s = wv; dst = wqkvb + 1310720; off = i - 5505024; }
  else { s = wp; dst = wpb; off = i - 5767168; }
  float4 v = s[off];
  bf16x4 o = {(__bf16)v.x, (__bf16)v.y, (__bf16)v.z, (__bf16)v.w};
  dst[off] = o;
}

// ---------------------------------------------------------------------------
// GEMM: C(MxN) = A(MxK) @ B(NxK)^T, bf16 in, fp32 acc. m97 structure.
// Used for the output projection (fp32 out).
// R3: T1 XCD-aware block swizzle (grid 16x64 = 1024 wg, 1024%8==0 ->
// simple remap is bijective). Each XCD gets a contiguous chunk of tile
// space (8 rows x 16 cols) -> A/B panel reuse lands in its private L2.
// ---------------------------------------------------------------------------
__global__ __launch_bounds__(256) void gemm_bt(const bf16_t* __restrict__ A,
                                               const bf16_t* __restrict__ B,
                                               void* __restrict__ Cp,
                                               int M, int N, int K, int out_bf16) {
  __shared__ bf16_t As[128 * 32];
  __shared__ bf16_t Bs[128 * 32];
  const int tid = threadIdx.x;
  const int w = tid >> 6, lane = tid & 63;
  const int m_lane = lane & 15, quad = lane >> 4;
  const int wr = w >> 1, wc = w & 1;
  int bid = blockIdx.y * gridDim.x + blockIdx.x;
  const int cpx = (gridDim.x * gridDim.y) >> 3;
  bid = (bid & 7) * cpx + (bid >> 3);
  const int rowBase = (bid / gridDim.x) * 128, colBase = (bid % gridDim.x) * 128;

  f32x4 acc[4][4];
#pragma unroll
  for (int i = 0; i < 4; ++i)
#pragma unroll
    for (int j = 0; j < 4; ++j) acc[i][j] = (f32x4){0.f, 0.f, 0.f, 0.f};

  const int nk = K >> 5;
  for (int kk = 0; kk < nk; ++kk) {
    const int k0 = kk << 5;
#pragma unroll
    for (int i2 = 0; i2 < 2; ++i2) {
      int idx = i2 * 256 + tid;
      int row = idx >> 2, kc = idx & 3;
      gload16(A + (size_t)(rowBase + row) * K + k0 + kc * 8, &As[idx * 8]);
      gload16(B + (size_t)(colBase + row) * K + k0 + kc * 8, &Bs[idx * 8]);
    }
    __syncthreads();
    bf16x8 a[4], bb[4];
#pragma unroll
    for (int i = 0; i < 4; ++i)
      a[i] = *(const bf16x8*)&As[(wr * 64 + i * 16 + m_lane) * 32 + quad * 8];
#pragma unroll
    for (int j = 0; j < 4; ++j)
      bb[j] = *(const bf16x8*)&Bs[(wc * 64 + j * 16 + m_lane) * 32 + quad * 8];
#pragma unroll
    for (int i = 0; i < 4; ++i)
#pragma unroll
      for (int j = 0; j < 4; ++j)
        acc[i][j] = __builtin_amdgcn_mfma_f32_16x16x32_bf16(a[i], bb[j], acc[i][j], 0, 0, 0);
    __syncthreads();
  }

  if (out_bf16) {
    bf16_t* C = (bf16_t*)Cp;
#pragma unroll
    for (int i = 0; i < 4; ++i)
#pragma unroll
      for (int j = 0; j < 4; ++j)
#pragma unroll
        for (int r = 0; r < 4; ++r) {
          int row = rowBase + wr * 64 + i * 16 + quad * 4 + r;
          int col = colBase + wc * 64 + j * 16 + m_lane;
          C[(size_t)row * N + col] = (bf16_t)acc[i][j][r];
        }
  } else {
    float* C = (float*)Cp;
#pragma unroll
    for (int i = 0; i < 4; ++i)
#pragma unroll
      for (int j = 0; j < 4; ++j)
#pragma unroll
        for (int r = 0; r < 4; ++r) {
          int row = rowBase + wr * 64 + i * 16 + quad * 4 + r;
          int col = colBase + wc * 64 + j * 16 + m_lane;
          C[(size_t)row * N + col] = acc[i][j][r];
        }
  }
}

// ---------------------------------------------------------------------------
// QKV GEMM with fused epilogue: M=8192, N=3072, K=2048.
// Col-tile bx: 0..15 = q heads, 16..19 = k heads, 20..23 = v heads.
// q/k tiles: RMSNorm (fp32 acc, cross-wave LDS reduce) + RoPE (+gain*QSCALE
// for q). A 128-col tile is exactly one head; RoPE pairs (d,d+32) are
// lane-local (fragment j and j+2). v tiles: raw store + transposed store
// into vt (B,KVH,HD,T) -- replaces the separate vtrans kernel.
// R3: T1 XCD swizzle (grid 24x64 = 1536 wg, 1536%8==0 -> bijective).
// ---------------------------------------------------------------------------
__global__ __launch_bounds__(256) void gemm_qkv(const bf16_t* __restrict__ A,
                                                const bf16_t* __restrict__ Bw,
                                                bf16_t* __restrict__ qkv,
                                                bf16_t* __restrict__ vt,
                                                const float* __restrict__ gain) {
  __shared__ bf16_t As[128 * 32];
  __shared__ bf16_t Bs[128 * 32];
  __shared__ float ssbuf[2][128];
  const int tid = threadIdx.x;
  const int w = tid >> 6, lane = tid & 63;
  const int m = lane & 15, quad = lane >> 4;
  const int wr = w >> 1, wc = w & 1;
  int bid = blockIdx.y * 24 + blockIdx.x;
  bid = (bid & 7) * 192 + (bid >> 3);
  const int bx = bid % 24, by = bid / 24;
  const int rowBase = by * 128, colBase = bx * 128;

  f32x4 acc[4][4];
#pragma unroll
  for (int i = 0; i < 4; ++i)
#pragma unroll
    for (int j = 0; j < 4; ++j) acc[i][j] = (f32x4){0.f, 0.f, 0.f, 0.f};

  for (int kk = 0; kk < 64; ++kk) {
    const int k0 = kk << 5;
#pragma unroll
    for (int i2 = 0; i2 < 2; ++i2) {
      int idx = i2 * 256 + tid;
      int row = idx >> 2, kc = idx & 3;
      gload16(A + (size_t)(rowBase + row) * 2048 + k0 + kc * 8, &As[idx * 8]);
      gload16(Bw + (size_t)(colBase + row) * 2048 + k0 + kc * 8, &Bs[idx * 8]);
    }
    __syncthreads();
    bf16x8 a[4], bb[4];
#pragma unroll
    for (int i = 0; i < 4; ++i)
      a[i] = *(const bf16x8*)&As[(wr * 64 + i * 16 + m) * 32 + quad * 8];
#pragma unroll
    for (int j = 0; j < 4; ++j)
      bb[j] = *(const bf16x8*)&Bs[(wc * 64 + j * 16 + m) * 32 + quad * 8];
#pragma unroll
    for (int i = 0; i < 4; ++i)
#pragma unroll
      for (int j = 0; j < 4; ++j)
        acc[i][j] = __builtin_amdgcn_mfma_f32_16x16x32_bf16(a[i], bb[j], acc[i][j], 0, 0, 0);
    __syncthreads();
  }

  if (bx < 20) {
    // ---- q/k epilogue: RMSNorm + RoPE
    const float g = (bx < 16) ? gain[bx] * QSCALE : 1.0f;
    // per-row sum of squares: in-lane (4 cols) -> 16-lane tree -> LDS cross-wave
#pragma unroll
    for (int i = 0; i < 4; ++i) {
      float ssp[4];
#pragma unroll
      for (int r = 0; r < 4; ++r) {
        float s = 0.f;
#pragma unroll
        for (int j = 0; j < 4; ++j) s += acc[i][j][r] * acc[i][j][r];
#pragma unroll
        for (int off = 1; off <= 8; off <<= 1) s += __shfl_xor(s, off);
        ssp[r] = s;
      }
      if (m == 0) {
#pragma unroll
        for (int r = 0; r < 4; ++r) ssbuf[wc][wr * 64 + i * 16 + quad * 4 + r] = ssp[r];
      }
    }
    __syncthreads();
    // inv_freq for this lane's two rope pair-indices p=m and p=16+m
    const float if0 = exp2f(-(float)m * 0.4152410118609203f);
    const float if1 = exp2f(-(float)(16 + m) * 0.4152410118609203f);
#pragma unroll
    for (int i = 0; i < 4; ++i) {
#pragma unroll
      for (int r = 0; r < 4; ++r) {
        const int ridx = wr * 64 + i * 16 + quad * 4 + r;
        const int row = rowBase + ridx;
        const float rn = rsqrtf((ssbuf[0][ridx] + ssbuf[1][ridx]) * (1.f / 128.f) + 1e-6f);
        float v0 = acc[i][0][r] * rn, v1 = acc[i][1][r] * rn;
        float v2 = acc[i][2][r] * rn, v3 = acc[i][3][r] * rn;
        float o0 = v0, o1 = v1, o2 = v2, o3 = v3;
        if (wc == 0) {  // cols 0..63 of head: rotate pairs (d, d+32)
          const float t = (float)(row & (T_ - 1));
          const float a0 = t * if0, a1 = t * if1;
          const float c0 = cosf(a0), s0 = sinf(a0);
          const float c1 = cosf(a1), s1 = sinf(a1);
          o0 = v0 * c0 - v2 * s0;
          o1 = v1 * c1 - v3 * s1;
          o2 = v2 * c0 + v0 * s0;
          o3 = v3 * c1 + v1 * s1;
        }
        bf16_t* out = qkv + (size_t)row * QKV_ + colBase + wc * 64 + m;
        out[0]  = (bf16_t)(o0 * g);
        out[16] = (bf16_t)(o1 * g);
        out[32] = (bf16_t)(o2 * g);
        out[48] = (bf16_t)(o3 * g);
      }
    }
  } else {
    // ---- v epilogue: raw row-major store + transposed store into vt
    const int kvh = bx - 20;
#pragma unroll
    for (int i = 0; i < 4; ++i)
#pragma unroll
      for (int j = 0; j < 4; ++j) {
        const int row0 = rowBase + wr * 64 + i * 16 + quad * 4;
        const int d = wc * 64 + j * 16 + m;
        bf16x4 pv;
#pragma unroll
        for (int r = 0; r < 4; ++r) {
          pv[r] = (bf16_t)acc[i][j][r];
          qkv[(size_t)(row0 + r) * QKV_ + colBase + d] = pv[r];
        }
        const int b = row0 >> 11, t0 = row0 & (T_ - 1);
        *(bf16x4*)(vt + ((size_t)(b * KVH_ + kvh) * HD_ + d) * T_ + t0) = pv;
      }
  }
}

// ---------------------------------------------------------------------------
// Flash attention, S^T formulation, software-pipelined. EXACT R0 structure
// (191us measured): grid (8,16,4), block handles q-tiles {15-x, x} (uniform
// 68 iters/block), unconditional online-softmax rescale (the R1/R2 T13
// branch regressed 191->282us: conditional in the inner loop wrecked the
// schedule -- do not reintroduce without .s evidence).
// 4 waves x 32 q-rows. K-step 32, double-buffered K/V LDS via
// global_load_lds. LDS read offsets hoisted out of the K-loop.
// ---------------------------------------------------------------------------
__global__ __launch_bounds__(256) void attn_kernel(const bf16_t* __restrict__ qkv,
                                                   const bf16_t* __restrict__ vt,
                                                   bf16_t* __restrict__ y) {
  __shared__ __align__(16) bf16_t Ks[2][32 * 128];  // [key][hd], chunk slot s holds src chunk s^(key&15)
  __shared__ __align__(16) bf16_t Vs[2][128 * 32];  // [d][key], slot c holds src chunk c^((d^(d>>2))&3)
  __shared__ __align__(16) bf16_t Ps[4][32 * 40];   // per-wave P [qrow][key], stride 40

  const int tid = threadIdx.x;
  const int w = tid >> 6, lane = tid & 63;
  const int m = lane & 15, q = lane >> 4;
  const int h = blockIdx.y, b = blockIdx.z, kvh = h >> 2;

  const bf16_t* qptr = qkv + (size_t)(b * T_) * QKV_ + h * HD_;
  const bf16_t* kptr = qkv + (size_t)(b * T_) * QKV_ + DIM_ + kvh * HD_;
  const bf16_t* vptr = qkv + (size_t)(b * T_) * QKV_ + DIM_ + KVH_ * HD_ + kvh * HD_;
  const bf16_t* vtptr = vt + (size_t)(b * KVH_ + kvh) * HD_ * T_;

  // per-thread staging indices (fixed): K 512 chunks, V 512 chunks
  const int kKey0 = tid >> 4, kC0 = tid & 15;
  const int kKey1 = (256 + tid) >> 4, kC1 = tid & 15;
  const int vD0 = tid >> 2, vC0 = tid & 3;
  const int vD1 = (256 + tid) >> 2, vC1 = tid & 3;
  const int vS0 = (vD0 ^ (vD0 >> 2)) & 3, vS1 = (vD1 ^ (vD1 >> 2)) & 3;

  // hoisted LDS read offsets (loop-invariant; elements)
  int koff[2][4], voff[8], poff[2];
#pragma unroll
  for (int kf = 0; kf < 2; ++kf)
#pragma unroll
    for (int c = 0; c < 4; ++c)
      koff[kf][c] = (kf * 16 + m) * 128 + (((c * 4 + q) ^ m) & 15) * 8;
#pragma unroll
  for (int f = 0; f < 8; ++f) {
    const int d = f * 16 + m;
    voff[f] = d * 32 + ((q ^ ((d ^ (d >> 2)) & 3)) & 3) * 8;
  }
#pragma unroll
  for (int qf = 0; qf < 2; ++qf) poff[qf] = (qf * 16 + m) * 40 + q * 8;

#pragma unroll 1
  for (int ti = 0; ti < 2; ++ti) {
    const int qb = ((ti == 0) ? (15 - (int)blockIdx.x) : (int)blockIdx.x) * 128;
    const int qbw = qb + w * 32;
    const int nk = (qb >> 5) + 4;

    // Q fragments (B-operand): aq[qf][c] = Q[qbw+qf*16+m][c*32+q*8 ..+8]
    bf16x8 aq[2][4];
#pragma unroll
    for (int qf = 0; qf < 2; ++qf)
#pragma unroll
      for (int c = 0; c < 4; ++c)
        aq[qf][c] = *(const bf16x8*)(qptr + (size_t)(qbw + qf * 16 + m) * QKV_ + c * 32 + q * 8);

    f32x4 o[2][8];
#pragma unroll
    for (int qf = 0; qf < 2; ++qf)
#pragma unroll
      for (int f = 0; f < 8; ++f) o[qf][f] = (f32x4){0.f, 0.f, 0.f, 0.f};
    float m_r[2] = {-1e30f, -1e30f};
    float l_r[2] = {0.f, 0.f};

    // prefetch tile 0 (elem offset = chunk_id * 8)
    {
      gload16(kptr + (size_t)kKey0 * QKV_ + ((kC0 ^ kKey0) & 15) * 8, &Ks[0][tid * 8]);
      gload16(kptr + (size_t)kKey1 * QKV_ + ((kC1 ^ kKey1) & 15) * 8, &Ks[0][(256 + tid) * 8]);
      gload16(vtptr + (size_t)vD0 * T_ + (vC0 ^ vS0) * 8, &Vs[0][tid * 8]);
      gload16(vtptr + (size_t)vD1 * T_ + (vC1 ^ vS1) * 8, &Vs[0][(256 + tid) * 8]);
    }

#pragma unroll 1
    for (int it = 0; it < nk; ++it) {
      const int kb = it << 5;
      __syncthreads();  // drains tile-it loads (issued one full iter ago)

      if (it + 1 < nk) {  // issue tile it+1 into the other buffer
        const int kb2 = kb + 32;
        bf16_t* Kb = Ks[(it + 1) & 1];
        bf16_t* Vb = Vs[(it + 1) & 1];
        gload16(kptr + (size_t)(kb2 + kKey0) * QKV_ + ((kC0 ^ kKey0) & 15) * 8, &Kb[tid * 8]);
        gload16(kptr + (size_t)(kb2 + kKey1) * QKV_ + ((kC1 ^ kKey1) & 15) * 8, &Kb[(256 + tid) * 8]);
        gload16(vtptr + (size_t)vD0 * T_ + kb2 + (vC0 ^ vS0) * 8, &Vb[tid * 8]);
        gload16(vtptr + (size_t)vD1 * T_ + kb2 + (vC1 ^ vS1) * 8, &Vb[(256 + tid) * 8]);
      }

      if (kb > qbw + 31) continue;  // whole key-tile masked for this wave
      const bf16_t* Kb = Ks[it & 1];
      const bf16_t* Vb = Vs[it & 1];

      // ---- S^T = K . Q^T   (16 MFMA, 8 ds_read_b128)
      f32x4 S[2][2];
#pragma unroll
      for (int qf = 0; qf < 2; ++qf)
#pragma unroll
        for (int kf = 0; kf < 2; ++kf) S[qf][kf] = (f32x4){0.f, 0.f, 0.f, 0.f};
#pragma unroll
      for (int kf = 0; kf < 2; ++kf)
#pragma unroll
        for (int c = 0; c < 4; ++c) {
          bf16x8 ak = *(const bf16x8*)&Kb[koff[kf][c]];
          S[0][kf] = __builtin_amdgcn_mfma_f32_16x16x32_bf16(ak, aq[0][c], S[0][kf], 0, 0, 0);
          S[1][kf] = __builtin_amdgcn_mfma_f32_16x16x32_bf16(ak, aq[1][c], S[1][kf], 0, 0, 0);
        }

      const bool needmask = (kb + 31) > qbw;
#pragma unroll
      for (int qf = 0; qf < 2; ++qf) {
        const int qrow = qbw + qf * 16 + m;
        if (needmask) {
#pragma unroll
          for (int kf = 0; kf < 2; ++kf)
#pragma unroll
            for (int r = 0; r < 4; ++r) {
              int key = kb + kf * 16 + q * 4 + r;
              if (key > qrow) S[qf][kf][r] = -1e30f;
            }
        }
        float t = -1e30f;
#pragma unroll
        for (int kf = 0; kf < 2; ++kf)
          t = fmaxf(t, fmaxf(fmaxf(S[qf][kf][0], S[qf][kf][1]),
                             fmaxf(S[qf][kf][2], S[qf][kf][3])));
        t = fmaxf(t, __shfl_xor(t, 16));
        t = fmaxf(t, __shfl_xor(t, 32));
        float mn = fmaxf(m_r[qf], t);
        float al = exp2f(m_r[qf] - mn);
        m_r[qf] = mn;
        float rs = 0.f;
#pragma unroll
        for (int kf = 0; kf < 2; ++kf)
#pragma unroll
          for (int r = 0; r < 4; ++r) {
            float p = exp2f(S[qf][kf][r] - mn);
            S[qf][kf][r] = p;
            rs += p;
          }
        rs += __shfl_xor(rs, 16);
        rs += __shfl_xor(rs, 32);
        l_r[qf] = l_r[qf] * al + rs;
#pragma unroll
        for (int f = 0; f < 8; ++f) o[qf][f] = o[qf][f] * al;  // f32x4 * scalar
#pragma unroll
        for (int kf = 0; kf < 2; ++kf) {
          bf16x4 pk = {(__bf16)S[qf][kf][0], (__bf16)S[qf][kf][1],
                       (__bf16)S[qf][kf][2], (__bf16)S[qf][kf][3]};
          *(bf16x4*)&Ps[w][(qf * 16 + m) * 40 + kf * 16 + q * 4] = pk;
        }
      }
      asm volatile("s_waitcnt lgkmcnt(0)" ::: "memory");

      // ---- PV: O^T += V^T . P^T  (16 MFMA, 10 ds_read_b128)
      bf16x8 Pb[2];
#pragma unroll
      for (int qf = 0; qf < 2; ++qf)
        Pb[qf] = *(const bf16x8*)&Ps[w][poff[qf]];
#pragma unroll
      for (int f = 0; f < 8; ++f) {
        bf16x8 av = *(const bf16x8*)&Vb[voff[f]];
        o[0][f] = __builtin_amdgcn_mfma_f32_16x16x32_bf16(av, Pb[0], o[0][f], 0, 0, 0);
        o[1][f] = __builtin_amdgcn_mfma_f32_16x16x32_bf16(av, Pb[1], o[1][f], 0, 0, 0);
      }
    }

    // ---- epilogue: y = o/l minus projection onto normalized v row
#pragma unroll
    for (int qf = 0; qf < 2; ++qf) {
      const int trow = qbw + qf * 16 + m;
      const float linv = 1.f / l_r[qf];
      bf16x4 vv[8];
      float n2 = 0.f, dp = 0.f;
#pragma unroll
      for (int f = 0; f < 8; ++f) {
        vv[f] = *(const bf16x4*)(vptr + (size_t)trow * QKV_ + f * 16 + q * 4);
#pragma unroll
        for (int r = 0; r < 4; ++r) {
          float v = (float)vv[f][r];
          n2 += v * v;
          dp += o[qf][f][r] * linv * v;
        }
      }
      n2 += __shfl_xor(n2, 16); n2 += __shfl_xor(n2, 32);
      dp += __shfl_xor(dp, 16); dp += __shfl_xor(dp, 32);
      float d = fmaxf(sqrtf(n2), 1e-12f);
      float coef = dp / (d * d);
#pragma unroll
      for (int f = 0; f < 8; ++f) {
        bf16x4 yo;
#pragma unroll
        for (int r = 0; r < 4; ++r)
          yo[r] = (bf16_t)(o[qf][f][r] * linv - coef * (float)vv[f][r]);
        *(bf16x4*)(y + (size_t)(b * T_ + trow) * DIM_ + h * HD_ + f * 16 + q * 4) = yo;
      }
    }
    __syncthreads();  // protect K/V buffers before next q-tile's prefetch
  }
}

// ---------------------------------------------------------------------------
extern "C" void kernel_launch(void* const* d_in, const int* in_sizes, int n_in,
                              void* d_out, int out_size, void* d_ws, size_t ws_size,
                              hipStream_t stream) {
  const float* x = (const float*)d_in[0];
  const float* Wq = (const float*)d_in[1];
  const float* Wk = (const float*)d_in[2];
  const float* Wv = (const float*)d_in[3];
  const float* Wp = (const float*)d_in[4];
  const float* qg = (const float*)d_in[5];

  bf16_t* xbf = (bf16_t*)d_ws;                        // 8192*2048
  bf16_t* wqkv = xbf + (size_t)8192 * 2048;           // 3072*2048
  bf16_t* wproj = wqkv + (size_t)3072 * 2048;         // 2048*2048
  bf16_t* qkv = wproj + (size_t)2048 * 2048;          // 8192*3072
  bf16_t* vt = qkv + (size_t)8192 * 3072;             // 16*128*2048
  bf16_t* ybf = xbf;                                  // reuse after gemm_qkv

  cvt_all<<<26624, 256, 0, stream>>>((const float4*)x, (const float4*)Wq,
                                     (const float4*)Wk, (const float4*)Wv,
                                     (const float4*)Wp, (bf16x4*)xbf,
                                     (bf16x4*)wqkv, (bf16x4*)wproj);
  gemm_qkv<<<dim3(24, 64), 256, 0, stream>>>(xbf, wqkv, qkv, vt, qg);
  attn_kernel<<<dim3(8, 16, 4), 256, 0, stream>>>(qkv, vt, ybf);
  gemm_bt<<<dim3(16, 64), 256, 0, stream>>>(ybf, wproj, d_out, 8192, 2048, 2048, 0);
}

// Round 4
// 551.779 us; speedup vs baseline: 1.2346x; 1.0653x over previous
//
#include <hip/hip_runtime.h>
#include <cstdint>
#include <cstddef>

typedef __bf16 bf16_t;
typedef __bf16 bf16x4 __attribute__((ext_vector_type(4)));
typedef __bf16 bf16x8 __attribute__((ext_vector_type(8)));
typedef float f32x4 __attribute__((ext_vector_type(4)));

#define B_ 4
#define T_ 2048
#define DIM_ 2048
#define H_ 16
#define KVH_ 4
#define HD_ 128
#define QKV_ 3072
// SCALE * log2(e): folded into q rows in the gemm_qkv epilogue; attn uses exp2.
#define QSCALE (0.08838834764831845f * 1.4426950408889634f)

// ---------------------------------------------------------------------------
// async global->LDS, 16B per lane. LDS dest = wave-uniform base + lane*16B.
// Dest pointer arithmetic is in ELEMENTS: 8 bf16 = 16B per lane.
// ---------------------------------------------------------------------------
__device__ __forceinline__ void gload16(const bf16_t* g, bf16_t* l) {
  __builtin_amdgcn_global_load_lds(
      (const __attribute__((address_space(1))) unsigned int*)g,
      (__attribute__((address_space(3))) unsigned int*)l, 16, 0, 0);
}

// ---------------------------------------------------------------------------
// fused fp32 -> bf16 convert for all five inputs (one launch).
// Segments (float4 units): x 4194304 | Wq 1048576 | Wk 262144 | Wv 262144 | Wp 1048576
// ---------------------------------------------------------------------------
__global__ __launch_bounds__(256) void cvt_all(const float4* __restrict__ x,
                                               const float4* __restrict__ wq,
                                               const float4* __restrict__ wk,
                                               const float4* __restrict__ wv,
                                               const float4* __restrict__ wp,
                                               bf16x4* __restrict__ xb,
                                               bf16x4* __restrict__ wqkvb,
                                               bf16x4* __restrict__ wpb) {
  int i = blockIdx.x * 256 + threadIdx.x;
  const float4* s;
  bf16x4* dst;
  int off;
  if (i < 4194304) { s = x; dst = xb; off = i; }
  else if (i < 5242880) { s = wq; dst = wqkvb; off = i - 4194304; }
  else if (i < 5505024) { s = wk; dst = wqkvb + 1048576; off = i - 5242880; }
  else if (i < 5767168) { s = wv; dst = wqkvb + 1310720; off = i - 5505024; }
  else { s = wp; dst = wpb; off = i - 5767168; }
  float4 v = s[off];
  bf16x4 o = {(__bf16)v.x, (__bf16)v.y, (__bf16)v.z, (__bf16)v.w};
  dst[off] = o;
}

// ---------------------------------------------------------------------------
// GEMM: C(MxN) = A(MxK) @ B(NxK)^T, bf16 in, fp32 acc. m97 structure.
// Used for the output projection (fp32 out). R4: XCD swizzle reverted
// (R3 measured it ~neutral-negative here: working sets are L3-fit).
// ---------------------------------------------------------------------------
__global__ __launch_bounds__(256) void gemm_bt(const bf16_t* __restrict__ A,
                                               const bf16_t* __restrict__ B,
                                               void* __restrict__ Cp,
                                               int M, int N, int K, int out_bf16) {
  __shared__ bf16_t As[128 * 32];
  __shared__ bf16_t Bs[128 * 32];
  const int tid = threadIdx.x;
  const int w = tid >> 6, lane = tid & 63;
  const int m_lane = lane & 15, quad = lane >> 4;
  const int wr = w >> 1, wc = w & 1;
  const int rowBase = blockIdx.y * 128, colBase = blockIdx.x * 128;

  f32x4 acc[4][4];
#pragma unroll
  for (int i = 0; i < 4; ++i)
#pragma unroll
    for (int j = 0; j < 4; ++j) acc[i][j] = (f32x4){0.f, 0.f, 0.f, 0.f};

  const int nk = K >> 5;
  for (int kk = 0; kk < nk; ++kk) {
    const int k0 = kk << 5;
#pragma unroll
    for (int i2 = 0; i2 < 2; ++i2) {
      int idx = i2 * 256 + tid;
      int row = idx >> 2, kc = idx & 3;
      gload16(A + (size_t)(rowBase + row) * K + k0 + kc * 8, &As[idx * 8]);
      gload16(B + (size_t)(colBase + row) * K + k0 + kc * 8, &Bs[idx * 8]);
    }
    __syncthreads();
    bf16x8 a[4], bb[4];
#pragma unroll
    for (int i = 0; i < 4; ++i)
      a[i] = *(const bf16x8*)&As[(wr * 64 + i * 16 + m_lane) * 32 + quad * 8];
#pragma unroll
    for (int j = 0; j < 4; ++j)
      bb[j] = *(const bf16x8*)&Bs[(wc * 64 + j * 16 + m_lane) * 32 + quad * 8];
#pragma unroll
    for (int i = 0; i < 4; ++i)
#pragma unroll
      for (int j = 0; j < 4; ++j)
        acc[i][j] = __builtin_amdgcn_mfma_f32_16x16x32_bf16(a[i], bb[j], acc[i][j], 0, 0, 0);
    __syncthreads();
  }

  if (out_bf16) {
    bf16_t* C = (bf16_t*)Cp;
#pragma unroll
    for (int i = 0; i < 4; ++i)
#pragma unroll
      for (int j = 0; j < 4; ++j)
#pragma unroll
        for (int r = 0; r < 4; ++r) {
          int row = rowBase + wr * 64 + i * 16 + quad * 4 + r;
          int col = colBase + wc * 64 + j * 16 + m_lane;
          C[(size_t)row * N + col] = (bf16_t)acc[i][j][r];
        }
  } else {
    float* C = (float*)Cp;
#pragma unroll
    for (int i = 0; i < 4; ++i)
#pragma unroll
      for (int j = 0; j < 4; ++j)
#pragma unroll
        for (int r = 0; r < 4; ++r) {
          int row = rowBase + wr * 64 + i * 16 + quad * 4 + r;
          int col = colBase + wc * 64 + j * 16 + m_lane;
          C[(size_t)row * N + col] = acc[i][j][r];
        }
  }
}

// ---------------------------------------------------------------------------
// QKV GEMM with fused epilogue: M=8192, N=3072, K=2048.
// Col-tile bx: 0..15 = q heads, 16..19 = k heads, 20..23 = v heads.
// q/k tiles: RMSNorm (fp32 acc, cross-wave LDS reduce) + RoPE (+gain*QSCALE
// for q). A 128-col tile is exactly one head; RoPE pairs (d,d+32) are
// lane-local (fragment j and j+2). v tiles: raw store + transposed store
// into vt (B,KVH,HD,T) -- replaces the separate vtrans kernel.
// ---------------------------------------------------------------------------
__global__ __launch_bounds__(256) void gemm_qkv(const bf16_t* __restrict__ A,
                                                const bf16_t* __restrict__ Bw,
                                                bf16_t* __restrict__ qkv,
                                                bf16_t* __restrict__ vt,
                                                const float* __restrict__ gain) {
  __shared__ bf16_t As[128 * 32];
  __shared__ bf16_t Bs[128 * 32];
  __shared__ float ssbuf[2][128];
  const int tid = threadIdx.x;
  const int w = tid >> 6, lane = tid & 63;
  const int m = lane & 15, quad = lane >> 4;
  const int wr = w >> 1, wc = w & 1;
  const int rowBase = blockIdx.y * 128, colBase = blockIdx.x * 128;

  f32x4 acc[4][4];
#pragma unroll
  for (int i = 0; i < 4; ++i)
#pragma unroll
    for (int j = 0; j < 4; ++j) acc[i][j] = (f32x4){0.f, 0.f, 0.f, 0.f};

  for (int kk = 0; kk < 64; ++kk) {
    const int k0 = kk << 5;
#pragma unroll
    for (int i2 = 0; i2 < 2; ++i2) {
      int idx = i2 * 256 + tid;
      int row = idx >> 2, kc = idx & 3;
      gload16(A + (size_t)(rowBase + row) * 2048 + k0 + kc * 8, &As[idx * 8]);
      gload16(Bw + (size_t)(colBase + row) * 2048 + k0 + kc * 8, &Bs[idx * 8]);
    }
    __syncthreads();
    bf16x8 a[4], bb[4];
#pragma unroll
    for (int i = 0; i < 4; ++i)
      a[i] = *(const bf16x8*)&As[(wr * 64 + i * 16 + m) * 32 + quad * 8];
#pragma unroll
    for (int j = 0; j < 4; ++j)
      bb[j] = *(const bf16x8*)&Bs[(wc * 64 + j * 16 + m) * 32 + quad * 8];
#pragma unroll
    for (int i = 0; i < 4; ++i)
#pragma unroll
      for (int j = 0; j < 4; ++j)
        acc[i][j] = __builtin_amdgcn_mfma_f32_16x16x32_bf16(a[i], bb[j], acc[i][j], 0, 0, 0);
    __syncthreads();
  }

  const int bx = blockIdx.x;
  if (bx < 20) {
    // ---- q/k epilogue: RMSNorm + RoPE
    const float g = (bx < 16) ? gain[bx] * QSCALE : 1.0f;
    // per-row sum of squares: in-lane (4 cols) -> 16-lane tree -> LDS cross-wave
#pragma unroll
    for (int i = 0; i < 4; ++i) {
      float ssp[4];
#pragma unroll
      for (int r = 0; r < 4; ++r) {
        float s = 0.f;
#pragma unroll
        for (int j = 0; j < 4; ++j) s += acc[i][j][r] * acc[i][j][r];
#pragma unroll
        for (int off = 1; off <= 8; off <<= 1) s += __shfl_xor(s, off);
        ssp[r] = s;
      }
      if (m == 0) {
#pragma unroll
        for (int r = 0; r < 4; ++r) ssbuf[wc][wr * 64 + i * 16 + quad * 4 + r] = ssp[r];
      }
    }
    __syncthreads();
    // inv_freq for this lane's two rope pair-indices p=m and p=16+m
    const float if0 = exp2f(-(float)m * 0.4152410118609203f);
    const float if1 = exp2f(-(float)(16 + m) * 0.4152410118609203f);
#pragma unroll
    for (int i = 0; i < 4; ++i) {
#pragma unroll
      for (int r = 0; r < 4; ++r) {
        const int ridx = wr * 64 + i * 16 + quad * 4 + r;
        const int row = rowBase + ridx;
        const float rn = rsqrtf((ssbuf[0][ridx] + ssbuf[1][ridx]) * (1.f / 128.f) + 1e-6f);
        float v0 = acc[i][0][r] * rn, v1 = acc[i][1][r] * rn;
        float v2 = acc[i][2][r] * rn, v3 = acc[i][3][r] * rn;
        float o0 = v0, o1 = v1, o2 = v2, o3 = v3;
        if (wc == 0) {  // cols 0..63 of head: rotate pairs (d, d+32)
          const float t = (float)(row & (T_ - 1));
          const float a0 = t * if0, a1 = t * if1;
          const float c0 = cosf(a0), s0 = sinf(a0);
          const float c1 = cosf(a1), s1 = sinf(a1);
          o0 = v0 * c0 - v2 * s0;
          o1 = v1 * c1 - v3 * s1;
          o2 = v2 * c0 + v0 * s0;
          o3 = v3 * c1 + v1 * s1;
        }
        bf16_t* out = qkv + (size_t)row * QKV_ + colBase + wc * 64 + m;
        out[0]  = (bf16_t)(o0 * g);
        out[16] = (bf16_t)(o1 * g);
        out[32] = (bf16_t)(o2 * g);
        out[48] = (bf16_t)(o3 * g);
      }
    }
  } else {
    // ---- v epilogue: raw row-major store + transposed store into vt
    const int kvh = bx - 20;
#pragma unroll
    for (int i = 0; i < 4; ++i)
#pragma unroll
      for (int j = 0; j < 4; ++j) {
        const int row0 = rowBase + wr * 64 + i * 16 + quad * 4;
        const int d = wc * 64 + j * 16 + m;
        bf16x4 pv;
#pragma unroll
        for (int r = 0; r < 4; ++r) {
          pv[r] = (bf16_t)acc[i][j][r];
          qkv[(size_t)(row0 + r) * QKV_ + colBase + d] = pv[r];
        }
        const int b = row0 >> 11, t0 = row0 & (T_ - 1);
        *(bf16x4*)(vt + ((size_t)(b * KVH_ + kvh) * HD_ + d) * T_ + t0) = pv;
      }
  }
}

// ---------------------------------------------------------------------------
// Flash attention, S^T formulation, software-pipelined. R4:
//  * NO-MAX softmax: q,k are RMS-normalized (RoPE = rotation, gain=1), so
//    |S| <= 128*QSCALE = 16.4 log2-units. exp2(S) <= 8.2e4, l <= 1.7e8 --
//    safely inside f32, and bf16 P has scale-invariant relative error.
//    Removes per-tile: row-max fmax tree + 2 shfl, al=exp2, l*al, and the
//    64-v_mul O-rescale. Unconditional (branchless) -- avoids the R1/R2
//    conditional-rescale schedule wreck (191->282us, reverted).
//    Masked entries: S=-1e30 -> exp2 underflows to exactly 0.
//  * grid (8,16,4): block handles q-tiles {15-x, x} -> uniform 68 iters.
// 4 waves x 32 q-rows. K-step 32, double-buffered K/V LDS via
// global_load_lds. LDS read offsets hoisted out of the K-loop.
// ---------------------------------------------------------------------------
__global__ __launch_bounds__(256) void attn_kernel(const bf16_t* __restrict__ qkv,
                                                   const bf16_t* __restrict__ vt,
                                                   bf16_t* __restrict__ y) {
  __shared__ __align__(16) bf16_t Ks[2][32 * 128];  // [key][hd], chunk slot s holds src chunk s^(key&15)
  __shared__ __align__(16) bf16_t Vs[2][128 * 32];  // [d][key], slot c holds src chunk c^((d^(d>>2))&3)
  __shared__ __align__(16) bf16_t Ps[4][32 * 40];   // per-wave P [qrow][key], stride 40

  const int tid = threadIdx.x;
  const int w = tid >> 6, lane = tid & 63;
  const int m = lane & 15, q = lane >> 4;
  const int h = blockIdx.y, b = blockIdx.z, kvh = h >> 2;

  const bf16_t* qptr = qkv + (size_t)(b * T_) * QKV_ + h * HD_;
  const bf16_t* kptr = qkv + (size_t)(b * T_) * QKV_ + DIM_ + kvh * HD_;
  const bf16_t* vptr = qkv + (size_t)(b * T_) * QKV_ + DIM_ + KVH_ * HD_ + kvh * HD_;
  const bf16_t* vtptr = vt + (size_t)(b * KVH_ + kvh) * HD_ * T_;

  // per-thread staging indices (fixed): K 512 chunks, V 512 chunks
  const int kKey0 = tid >> 4, kC0 = tid & 15;
  const int kKey1 = (256 + tid) >> 4, kC1 = tid & 15;
  const int vD0 = tid >> 2, vC0 = tid & 3;
  const int vD1 = (256 + tid) >> 2, vC1 = tid & 3;
  const int vS0 = (vD0 ^ (vD0 >> 2)) & 3, vS1 = (vD1 ^ (vD1 >> 2)) & 3;

  // hoisted LDS read offsets (loop-invariant; elements)
  int koff[2][4], voff[8], poff[2];
#pragma unroll
  for (int kf = 0; kf < 2; ++kf)
#pragma unroll
    for (int c = 0; c < 4; ++c)
      koff[kf][c] = (kf * 16 + m) * 128 + (((c * 4 + q) ^ m) & 15) * 8;
#pragma unroll
  for (int f = 0; f < 8; ++f) {
    const int d = f * 16 + m;
    voff[f] = d * 32 + ((q ^ ((d ^ (d >> 2)) & 3)) & 3) * 8;
  }
#pragma unroll
  for (int qf = 0; qf < 2; ++qf) poff[qf] = (qf * 16 + m) * 40 + q * 8;

#pragma unroll 1
  for (int ti = 0; ti < 2; ++ti) {
    const int qb = ((ti == 0) ? (15 - (int)blockIdx.x) : (int)blockIdx.x) * 128;
    const int qbw = qb + w * 32;
    const int nk = (qb >> 5) + 4;

    // Q fragments (B-operand): aq[qf][c] = Q[qbw+qf*16+m][c*32+q*8 ..+8]
    bf16x8 aq[2][4];
#pragma unroll
    for (int qf = 0; qf < 2; ++qf)
#pragma unroll
      for (int c = 0; c < 4; ++c)
        aq[qf][c] = *(const bf16x8*)(qptr + (size_t)(qbw + qf * 16 + m) * QKV_ + c * 32 + q * 8);

    f32x4 o[2][8];
#pragma unroll
    for (int qf = 0; qf < 2; ++qf)
#pragma unroll
      for (int f = 0; f < 8; ++f) o[qf][f] = (f32x4){0.f, 0.f, 0.f, 0.f};
    float l_r[2] = {0.f, 0.f};

    // prefetch tile 0 (elem offset = chunk_id * 8)
    {
      gload16(kptr + (size_t)kKey0 * QKV_ + ((kC0 ^ kKey0) & 15) * 8, &Ks[0][tid * 8]);
      gload16(kptr + (size_t)kKey1 * QKV_ + ((kC1 ^ kKey1) & 15) * 8, &Ks[0][(256 + tid) * 8]);
      gload16(vtptr + (size_t)vD0 * T_ + (vC0 ^ vS0) * 8, &Vs[0][tid * 8]);
      gload16(vtptr + (size_t)vD1 * T_ + (vC1 ^ vS1) * 8, &Vs[0][(256 + tid) * 8]);
    }

#pragma unroll 1
    for (int it = 0; it < nk; ++it) {
      const int kb = it << 5;
      __syncthreads();  // drains tile-it loads (issued one full iter ago)

      if (it + 1 < nk) {  // issue tile it+1 into the other buffer
        const int kb2 = kb + 32;
        bf16_t* Kb = Ks[(it + 1) & 1];
        bf16_t* Vb = Vs[(it + 1) & 1];
        gload16(kptr + (size_t)(kb2 + kKey0) * QKV_ + ((kC0 ^ kKey0) & 15) * 8, &Kb[tid * 8]);
        gload16(kptr + (size_t)(kb2 + kKey1) * QKV_ + ((kC1 ^ kKey1) & 15) * 8, &Kb[(256 + tid) * 8]);
        gload16(vtptr + (size_t)vD0 * T_ + kb2 + (vC0 ^ vS0) * 8, &Vb[tid * 8]);
        gload16(vtptr + (size_t)vD1 * T_ + kb2 + (vC1 ^ vS1) * 8, &Vb[(256 + tid) * 8]);
      }

      if (kb > qbw + 31) continue;  // whole key-tile masked for this wave
      const bf16_t* Kb = Ks[it & 1];
      const bf16_t* Vb = Vs[it & 1];

      // ---- S^T = K . Q^T   (16 MFMA, 8 ds_read_b128)
      f32x4 S[2][2];
#pragma unroll
      for (int qf = 0; qf < 2; ++qf)
#pragma unroll
        for (int kf = 0; kf < 2; ++kf) S[qf][kf] = (f32x4){0.f, 0.f, 0.f, 0.f};
#pragma unroll
      for (int kf = 0; kf < 2; ++kf)
#pragma unroll
        for (int c = 0; c < 4; ++c) {
          bf16x8 ak = *(const bf16x8*)&Kb[koff[kf][c]];
          S[0][kf] = __builtin_amdgcn_mfma_f32_16x16x32_bf16(ak, aq[0][c], S[0][kf], 0, 0, 0);
          S[1][kf] = __builtin_amdgcn_mfma_f32_16x16x32_bf16(ak, aq[1][c], S[1][kf], 0, 0, 0);
        }

      const bool needmask = (kb + 31) > qbw;
#pragma unroll
      for (int qf = 0; qf < 2; ++qf) {
        const int qrow = qbw + qf * 16 + m;
        if (needmask) {
#pragma unroll
          for (int kf = 0; kf < 2; ++kf)
#pragma unroll
            for (int r = 0; r < 4; ++r) {
              int key = kb + kf * 16 + q * 4 + r;
              if (key > qrow) S[qf][kf][r] = -1e30f;
            }
        }
        // no-max softmax: p = exp2(S) directly (scores bounded, see header)
        float rs = 0.f;
#pragma unroll
        for (int kf = 0; kf < 2; ++kf)
#pragma unroll
          for (int r = 0; r < 4; ++r) {
            float p = exp2f(S[qf][kf][r]);
            S[qf][kf][r] = p;
            rs += p;
          }
        rs += __shfl_xor(rs, 16);
        rs += __shfl_xor(rs, 32);
        l_r[qf] += rs;
#pragma unroll
        for (int kf = 0; kf < 2; ++kf) {
          bf16x4 pk = {(__bf16)S[qf][kf][0], (__bf16)S[qf][kf][1],
                       (__bf16)S[qf][kf][2], (__bf16)S[qf][kf][3]};
          *(bf16x4*)&Ps[w][(qf * 16 + m) * 40 + kf * 16 + q * 4] = pk;
        }
      }
      asm volatile("s_waitcnt lgkmcnt(0)" ::: "memory");

      // ---- PV: O^T += V^T . P^T  (16 MFMA, 10 ds_read_b128)
      bf16x8 Pb[2];
#pragma unroll
      for (int qf = 0; qf < 2; ++qf)
        Pb[qf] = *(const bf16x8*)&Ps[w][poff[qf]];
#pragma unroll
      for (int f = 0; f < 8; ++f) {
        bf16x8 av = *(const bf16x8*)&Vb[voff[f]];
        o[0][f] = __builtin_amdgcn_mfma_f32_16x16x32_bf16(av, Pb[0], o[0][f], 0, 0, 0);
        o[1][f] = __builtin_amdgcn_mfma_f32_16x16x32_bf16(av, Pb[1], o[1][f], 0, 0, 0);
      }
    }

    // ---- epilogue: y = o/l minus projection onto normalized v row
#pragma unroll
    for (int qf = 0; qf < 2; ++qf) {
      const int trow = qbw + qf * 16 + m;
      const float linv = 1.f / l_r[qf];
      bf16x4 vv[8];
      float n2 = 0.f, dp = 0.f;
#pragma unroll
      for (int f = 0; f < 8; ++f) {
        vv[f] = *(const bf16x4*)(vptr + (size_t)trow * QKV_ + f * 16 + q * 4);
#pragma unroll
        for (int r = 0; r < 4; ++r) {
          float v = (float)vv[f][r];
          n2 += v * v;
          dp += o[qf][f][r] * linv * v;
        }
      }
      n2 += __shfl_xor(n2, 16); n2 += __shfl_xor(n2, 32);
      dp += __shfl_xor(dp, 16); dp += __shfl_xor(dp, 32);
      float d = fmaxf(sqrtf(n2), 1e-12f);
      float coef = dp / (d * d);
#pragma unroll
      for (int f = 0; f < 8; ++f) {
        bf16x4 yo;
#pragma unroll
        for (int r = 0; r < 4; ++r)
          yo[r] = (bf16_t)(o[qf][f][r] * linv - coef * (float)vv[f][r]);
        *(bf16x4*)(y + (size_t)(b * T_ + trow) * DIM_ + h * HD_ + f * 16 + q * 4) = yo;
      }
    }
    __syncthreads();  // protect K/V buffers before next q-tile's prefetch
  }
}

// ---------------------------------------------------------------------------
extern "C" void kernel_launch(void* const* d_in, const int* in_sizes, int n_in,
                              void* d_out, int out_size, void* d_ws, size_t ws_size,
                              hipStream_t stream) {
  const float* x = (const float*)d_in[0];
  const float* Wq = (const float*)d_in[1];
  const float* Wk = (const float*)d_in[2];
  const float* Wv = (const float*)d_in[3];
  const float* Wp = (const float*)d_in[4];
  const float* qg = (const float*)d_in[5];

  bf16_t* xbf = (bf16_t*)d_ws;                        // 8192*2048
  bf16_t* wqkv = xbf + (size_t)8192 * 2048;           // 3072*2048
  bf16_t* wproj = wqkv + (size_t)3072 * 2048;         // 2048*2048
  bf16_t* qkv = wproj + (size_t)2048 * 2048;          // 8192*3072
  bf16_t* vt = qkv + (size_t)8192 * 3072;             // 16*128*2048
  bf16_t* ybf = xbf;                                  // reuse after gemm_qkv

  cvt_all<<<26624, 256, 0, stream>>>((const float4*)x, (const float4*)Wq,
                                     (const float4*)Wk, (const float4*)Wv,
                                     (const float4*)Wp, (bf16x4*)xbf,
                                     (bf16x4*)wqkv, (bf16x4*)wproj);
  gemm_qkv<<<dim3(24, 64), 256, 0, stream>>>(xbf, wqkv, qkv, vt, qg);
  attn_kernel<<<dim3(8, 16, 4), 256, 0, stream>>>(qkv, vt, ybf);
  gemm_bt<<<dim3(16, 64), 256, 0, stream>>>(ybf, wproj, d_out, 8192, 2048, 2048, 0);
}